// Round 5
// baseline (250.446 us; speedup 1.0000x reference)
//
#include <hip/hip_runtime.h>

// BilinearSamplerLayer: image [16,256,256,32] f32, flow [16,256,256,2] f32
// -> out [16,256,256,32] f32.
// 8 lanes per pixel, one float4 channel-quad per lane.
// 4 pixels per thread (strided by NPIX/4) for memory-level parallelism:
// 16 independent image gathers in flight per thread vs 4 in the baseline,
// which was latency-bound at 42% HBM peak (traffic was already minimal).
// Uses clang ext_vector f32x4 (native vector) so __builtin_nontemporal_store
// accepts it (HIP_vector_type float4 is rejected by the builtin).

using f32x4 = __attribute__((ext_vector_type(4))) float;

__global__ __launch_bounds__(256) void bilinear_sampler_kernel(
    const float* __restrict__ image,
    const float* __restrict__ flow,
    float* __restrict__ out)
{
    constexpr int H = 256, W = 256, C = 32;
    constexpr int NPIX = 16 * H * W;          // 1,048,576
    constexpr int PPT = 4;                    // pixels per thread
    constexpr int PSTRIDE = NPIX / PPT;       // 262,144

    const int gid  = blockIdx.x * 256 + threadIdx.x; // 2,097,152 threads
    const int pid0 = gid >> 3;                       // [0, PSTRIDE)
    const int cq   = (gid & 7) << 2;                 // channel offset 0..28

    float wa[PPT], wb[PPT], wc[PPT], wd[PPT];
    size_t a_a[PPT], a_b[PPT], a_c[PPT], a_d[PPT];

    // Phase 1: flow loads + address/weight math for all PPT pixels
    // (independent chains; compiler interleaves the flow loads).
#pragma unroll
    for (int k = 0; k < PPT; ++k) {
        const int pid = pid0 + k * PSTRIDE;
        const int b   = pid >> 16;
        const int rem = pid & 65535;
        const int yi  = rem >> 8;
        const int xi  = rem & 255;

        const float2 f = *reinterpret_cast<const float2*>(flow + (size_t)pid * 2);

        const float x_base = fmaf((float)xi, 2.0f / 255.0f, -1.0f);
        const float y_base = fmaf((float)yi, 2.0f / 255.0f, -1.0f);

        float x = fmaf(0.3f, f.x, x_base);
        float y = fmaf(0.3f, f.y, y_base);
        x = (x + 1.0f) * (0.5f * (float)W);   // reference uses W/2, not (W-1)/2
        y = (y + 1.0f) * (0.5f * (float)H);

        int x0 = (int)floorf(x);
        int y0 = (int)floorf(y);
        int x1 = x0 + 1;
        int y1 = y0 + 1;
        x0 = min(max(x0, 0), W - 1);
        x1 = min(max(x1, 0), W - 1);
        y0 = min(max(y0, 0), H - 1);
        y1 = min(max(y1, 0), H - 1);

        const float x0f = (float)x0, x1f = (float)x1;
        const float y0f = (float)y0, y1f = (float)y1;
        wa[k] = (x1f - x) * (y1f - y);
        wb[k] = (x1f - x) * (y - y0f);
        wc[k] = (x - x0f) * (y1f - y);
        wd[k] = (x - x0f) * (y - y0f);

        const int base = b << 16;
        const size_t row0 = (size_t)(base + y0 * W) * C;
        const size_t row1 = (size_t)(base + y1 * W) * C;
        a_a[k] = row0 + (size_t)x0 * C + cq;
        a_b[k] = row1 + (size_t)x0 * C + cq;
        a_c[k] = row0 + (size_t)x1 * C + cq;
        a_d[k] = row1 + (size_t)x1 * C + cq;
    }

    // Phase 2: issue all 16 gathers (independent — all in flight together).
    f32x4 Ia[PPT], Ib[PPT], Ic[PPT], Id[PPT];
#pragma unroll
    for (int k = 0; k < PPT; ++k) {
        Ia[k] = *reinterpret_cast<const f32x4*>(image + a_a[k]);
        Ib[k] = *reinterpret_cast<const f32x4*>(image + a_b[k]);
        Ic[k] = *reinterpret_cast<const f32x4*>(image + a_c[k]);
        Id[k] = *reinterpret_cast<const f32x4*>(image + a_d[k]);
    }

    // Phase 3: blend + non-temporal store (out is never re-read; keep it
    // from evicting L3-resident image lines).
#pragma unroll
    for (int k = 0; k < PPT; ++k) {
        const int pid = pid0 + k * PSTRIDE;
        f32x4 o = wa[k] * Ia[k] + wb[k] * Ib[k] + wc[k] * Ic[k] + wd[k] * Id[k];
        __builtin_nontemporal_store(o, reinterpret_cast<f32x4*>(out + (size_t)pid * C + cq));
    }
}

extern "C" void kernel_launch(void* const* d_in, const int* in_sizes, int n_in,
                              void* d_out, int out_size, void* d_ws, size_t ws_size,
                              hipStream_t stream) {
    const float* image = (const float*)d_in[0];
    const float* flow  = (const float*)d_in[1];
    float* out = (float*)d_out;

    // threads = B*H*W*C/4 / PPT = 2,097,152 ; block = 256
    const int blocks = 2097152 / 256; // 8192
    bilinear_sampler_kernel<<<blocks, 256, 0, stream>>>(image, flow, out);
}